// Round 12
// baseline (231.251 us; speedup 1.0000x reference)
//
#include <hip/hip_runtime.h>
#include <hip/hip_bf16.h>

#define D 384
#define NROWS 16384
#define BATCH 4
#define MG 512
#define RTOT (BATCH * NROWS) /* 65536 */
#define NC (2 * D)           /* 768 combined B rows: g|f panels per j-block */
#define JB 64                /* j-columns per panel */
#define NJB (D / JB)         /* 6 */
#define NKT 12               /* K-steps of 32 */

typedef __attribute__((ext_vector_type(8))) short bf16x8;
typedef __attribute__((ext_vector_type(4))) float f32x4;

static __device__ __forceinline__ unsigned short f2bf(float f) {
  unsigned int u = __float_as_uint(f);
  unsigned int r = u + 0x7fffu + ((u >> 16) & 1u); // RNE
  return (unsigned short)(r >> 16);
}
static __device__ __forceinline__ unsigned int cvtpk(float lo, float hi) {
  unsigned int r;
  asm("v_cvt_pk_bf16_f32 %0, %1, %2" : "=v"(r) : "v"(lo), "v"(hi));
  return r;
}
static __device__ __forceinline__ float frcp(float f) {
  float r;
  asm("v_rcp_f32 %0, %1" : "=v"(r) : "v"(f));
  return r;
}

// ---------------- preprocessing: CSR + zero s12 + weights bf16 ----------------
__global__ __launch_bounds__(512) void k_prep(
    const int* __restrict__ ii, const float* __restrict__ g_w,
    const float* __restrict__ f_w, const float* __restrict__ h_w,
    unsigned short* __restrict__ wt2, unsigned short* __restrict__ hw,
    int* __restrict__ csr_rows, int* __restrict__ grp_sorted,
    float* __restrict__ s12) {
  __shared__ int cnt[MG];
  __shared__ int scan[MG];
  const int blk = blockIdx.x;
  const int t = threadIdx.x; // 512 threads
  if (blk == 0) {
    cnt[t] = 0;
    __syncthreads();
    for (int n = t; n < NROWS; n += MG) atomicAdd(&cnt[ii[n]], 1);
    __syncthreads();
    const int v = cnt[t];
    scan[t] = v;
    __syncthreads();
#pragma unroll
    for (int o = 1; o < MG; o <<= 1) { // Hillis-Steele inclusive scan
      int u = (t >= o) ? scan[t - o] : 0;
      __syncthreads();
      scan[t] += u;
      __syncthreads();
    }
    cnt[t] = scan[t] - v; // exclusive
    __syncthreads();
    for (int n = t; n < NROWS; n += MG) {
      int m = ii[n];
      int pos = atomicAdd(&cnt[m], 1);
      csr_rows[pos] = n;
      grp_sorted[pos] = m;
    }
  } else if (blk < 64) {
    const int tot4 = 2 * BATCH * MG * D / 4;
    float4 z = {0.f, 0.f, 0.f, 0.f};
    for (int i = (blk - 1) * 512 + t; i < tot4; i += 63 * 512) ((float4*)s12)[i] = z;
  } else {
    const int tid0 = (blk - 64) * 512 + t;
    const int stride = 64 * 512;
    for (int idx = tid0; idx < NC * D; idx += stride) {
      int jblk = idx / (128 * D);
      int rem = idx % (128 * D);
      int c = rem / D, k = rem % D;
      int j = jblk * JB + (c & 63);
      float v = (c < JB) ? g_w[j * D + k] : f_w[j * D + k];
      wt2[idx] = f2bf(v);
    }
    for (int idx = tid0; idx < D * D; idx += stride) hw[idx] = f2bf(h_w[idx]);
  }
}

// ---------------- fused GEMM + exp + segment-reduce, barrier-free k-loop ----------------
// Block = 64 CSR rows, 256 threads (4 waves = 2 panels x 2 halves), grid 1024.
// A staged ONCE from f32 x (cvt_pk, XOR-swizzled, 48 KB LDS); ONE barrier.
// B fragments per-wave-private: direct global->reg from L2-hot wt2 with a
// 2-ahead named-register pipeline. 2 blocks/CU, VGPR cap 256 (no spill).
__global__ __launch_bounds__(256, 2) void k_gemm1(
    const float* __restrict__ x, const unsigned short* __restrict__ wt2,
    const float* __restrict__ g_b, const float* __restrict__ f_b,
    const int* __restrict__ csr_rows, const int* __restrict__ grp_sorted,
    float* __restrict__ s1acc, float* __restrict__ s2acc) {
  __shared__ __attribute__((aligned(16))) unsigned short As[NKT * 2048]; // 48 KiB resident
  __shared__ int grpS[64];

  const int tid = threadIdx.x;
  const int lane = tid & 63, wid = tid >> 6; // 4 waves
  const int p = wid >> 1;     // panel within item
  const int u = wid & 1;      // 32-j half within panel
  const int blk = blockIdx.x; // 0..1023
  const int b = blk >> 8;     // batch
  const int ibl = (blk & 255) * 64;

  if (tid < 64) grpS[tid] = grp_sorted[ibl + tid];

  const int swz16 = ((lane >> 4) ^ ((lane >> 1) & 3)) * 16; // swizzled read slot

  // B fragment base pointers (per-lane, direct global; kt*32 folds to imm)
  const unsigned short* bP[4];
#pragma unroll
  for (int n = 0; n < 4; n++) {
    const int c = (n < 2) ? (u * 32 + n * 16) : (64 + u * 32 + (n - 2) * 16);
    bP[n] = wt2 + (size_t)(c + (lane & 15)) * D + (lane >> 4) * 8;
  }

  bf16x8 b0[4], b1[4];

#define LOADB(Bv, jb_, kt_)                                                    \
  _Pragma("unroll") for (int n = 0; n < 4; n++) Bv[n] =                        \
      *(const bf16x8*)(bP[n] + (size_t)(jb_) * (128 * D) + (kt_) * 32);

#define STEPK(kt_, Bv)                                                         \
  _Pragma("unroll") for (int m = 0; m < 4; m++) {                              \
    const bf16x8 af = *(const bf16x8*)((const char*)As + (kt_) * 4096 +        \
        (m * 16 + (lane & 15)) * 64 + swz16);                                  \
    _Pragma("unroll") for (int n = 0; n < 4; n++)                              \
      acc[m][n] =                                                              \
          __builtin_amdgcn_mfma_f32_16x16x32_bf16(af, Bv[n], acc[m][n], 0, 0, 0); \
  }

  // issue item-0 B(kt=0) loads first (latency hides under A staging)
  LOADB(b0, p, 0)

  // ---- stage A once: f32 -> cvt_pk -> swizzled LDS, K-resident ----
  {
    const int arow = tid >> 2; // 0..63
    const int grow = csr_rows[ibl + arow];
    const float* asrc = x + ((size_t)((b << 14) + grow)) * D + (tid & 3) * 8;
    const int aslot = (tid & 3) ^ ((tid >> 3) & 3); // slot ^ ((row>>1)&3)
    char* adst = (char*)As + arow * 64 + aslot * 16;
#pragma unroll
    for (int kt = 0; kt < NKT; ++kt) {
      const float4 v0 = *(const float4*)(asrc + kt * 32);
      const float4 v1 = *(const float4*)(asrc + kt * 32 + 4);
      int4 o;
      o.x = cvtpk(v0.x, v0.y);
      o.y = cvtpk(v0.z, v0.w);
      o.z = cvtpk(v1.x, v1.y);
      o.w = cvtpk(v1.z, v1.w);
      *(int4*)(adst + kt * 4096) = o;
    }
  }
  __syncthreads(); // the ONLY barrier: A (and grpS) visible to all waves

  f32x4 acc[4][4];
#pragma unroll
  for (int m = 0; m < 4; m++)
#pragma unroll
    for (int n = 0; n < 4; n++) acc[m][n] = (f32x4){0.f, 0.f, 0.f, 0.f};

#pragma unroll 1
  for (int e = 0; e < 3; ++e) {
    const int jb = 2 * e + p;
#pragma unroll
    for (int k2 = 0; k2 < 6; ++k2) {
      const int kt = 2 * k2;
      LOADB(b1, jb, kt + 1)
      __builtin_amdgcn_s_setprio(1);
      STEPK(kt, b0)
      __builtin_amdgcn_s_setprio(0);
      if (kt + 2 < NKT) {
        LOADB(b0, jb, kt + 2)
      } else if (e < 2) {
        LOADB(b0, jb + 2, 0) // prefetch next item's first B under STEP(11)+epilogue
      }
      __builtin_amdgcn_s_setprio(1);
      STEPK(kt + 1, b1)
      __builtin_amdgcn_s_setprio(0);
    }

    // ---- epilogue for item e (panel jb): exp/bias + per-group reduce ----
    {
      const int j0 = jb * JB;
      const int jA = j0 + u * 32 + (lane & 15);
      const float gb0 = g_b[jA], gb1 = g_b[jA + 16];
      const float fb0 = f_b[jA], fb1 = f_b[jA + 16];

      int gmr[4][4];
#pragma unroll
      for (int m = 0; m < 4; m++)
#pragma unroll
        for (int r = 0; r < 4; r++)
          gmr[m][r] = grpS[m * 16 + (lane >> 4) * 4 + r];

#pragma unroll
      for (int m = 0; m < 4; m++)
#pragma unroll
        for (int r = 0; r < 4; r++) {
          const float e0 = expf(acc[m][0][r] + gb0);
          const float e1 = expf(acc[m][1][r] + gb1);
          const float f0 = acc[m][2][r] + fb0;
          const float f1 = acc[m][3][r] + fb1;
          acc[m][0][r] = e0; acc[m][1][r] = e1;
          acc[m][2][r] = f0 * e0; acc[m][3][r] = f1 * e1;
        }

      const int gLo = grpS[0], gHi = grpS[63];
      for (int g = gLo; g <= gHi; ++g) {
        float v0 = 0.f, v1 = 0.f, v2 = 0.f, v3 = 0.f;
#pragma unroll
        for (int m = 0; m < 4; m++)
#pragma unroll
          for (int r = 0; r < 4; r++)
            if (gmr[m][r] == g) {
              v0 += acc[m][0][r]; v1 += acc[m][1][r];
              v2 += acc[m][2][r]; v3 += acc[m][3][r];
            }
        v0 += __shfl_xor(v0, 16); v0 += __shfl_xor(v0, 32);
        v1 += __shfl_xor(v1, 16); v1 += __shfl_xor(v1, 32);
        v2 += __shfl_xor(v2, 16); v2 += __shfl_xor(v2, 32);
        v3 += __shfl_xor(v3, 16); v3 += __shfl_xor(v3, 32);
        if (lane < 16) {
          float* s1p = s1acc + ((size_t)(b * MG + g)) * D + j0 + u * 32 + lane;
          float* s2p = s2acc + ((size_t)(b * MG + g)) * D + j0 + u * 32 + lane;
          atomicAdd(s1p, v0);
          atomicAdd(s1p + 16, v1);
          atomicAdd(s2p, v2);
          atomicAdd(s2p + 16, v3);
        }
      }
    }
    // reset accumulators for next item
#pragma unroll
    for (int m = 0; m < 4; m++)
#pragma unroll
      for (int n = 0; n < 4; n++) acc[m][n] = (f32x4){0.f, 0.f, 0.f, 0.f};
  }
#undef LOADB
#undef STEPK
}

// ---------------- small GEMM with fused normalize ----------------
__global__ __launch_bounds__(256) void k_gemm2(
    const float* __restrict__ s1, const float* __restrict__ s2,
    const unsigned short* __restrict__ hw, const float* __restrict__ h_b,
    float* __restrict__ outpre) {
  const int tid = threadIdx.x, lane = tid & 63, wid = tid >> 6;
  const int r0 = blockIdx.y * 16;
  const int c0 = blockIdx.x * 64 + wid * 16;
  f32x4 acc = (f32x4){0.f, 0.f, 0.f, 0.f};
  const int arow = r0 + (lane & 15);
  const float* s1p = s1 + (size_t)arow * D + (lane >> 4) * 8;
  const float* s2p = s2 + (size_t)arow * D + (lane >> 4) * 8;
  const unsigned short* bRow = hw + (size_t)(c0 + (lane & 15)) * D + (lane >> 4) * 8;
#pragma unroll
  for (int kt = 0; kt < D / 32; kt++) {
    float4 u0 = *(const float4*)(s1p + kt * 32);
    float4 u1 = *(const float4*)(s1p + kt * 32 + 4);
    float4 w0 = *(const float4*)(s2p + kt * 32);
    float4 w1 = *(const float4*)(s2p + kt * 32 + 4);
    int4 yi;
    yi.x = cvtpk(w0.x * frcp(u0.x + 1e-6f), w0.y * frcp(u0.y + 1e-6f));
    yi.y = cvtpk(w0.z * frcp(u0.z + 1e-6f), w0.w * frcp(u0.w + 1e-6f));
    yi.z = cvtpk(w1.x * frcp(u1.x + 1e-6f), w1.y * frcp(u1.y + 1e-6f));
    yi.w = cvtpk(w1.z * frcp(u1.z + 1e-6f), w1.w * frcp(u1.w + 1e-6f));
    bf16x8 af = *(bf16x8*)&yi;
    bf16x8 bf_ = *(const bf16x8*)(bRow + kt * 32);
    acc = __builtin_amdgcn_mfma_f32_16x16x32_bf16(af, bf_, acc, 0, 0, 0);
  }
  const int col = c0 + (lane & 15);
  const float hb = h_b[col];
#pragma unroll
  for (int r = 0; r < 4; r++) {
    const int row = r0 + (lane >> 4) * 4 + r;
    outpre[(size_t)row * D + col] = acc[r] + hb;
  }
}

// ---------------- gather rows ----------------
__global__ void k_gather(const float* __restrict__ outpre, const int* __restrict__ ii,
                         float* __restrict__ out) {
  const long total4 = (long)RTOT * (D / 4); // 96 float4 per row
  for (long i = blockIdx.x * (long)blockDim.x + threadIdx.x; i < total4;
       i += (long)gridDim.x * blockDim.x) {
    const long row = i / (D / 4);
    const int q = (int)(i % (D / 4));
    const int b = (int)(row >> 14);
    const int n = (int)(row & (NROWS - 1));
    const int g = ii[n];
    ((float4*)out)[i] = ((const float4*)outpre)[((size_t)(b * MG + g)) * (D / 4) + q];
  }
}

extern "C" void kernel_launch(void* const* d_in, const int* in_sizes, int n_in,
                              void* d_out, int out_size, void* d_ws, size_t ws_size,
                              hipStream_t stream) {
  const float* x = (const float*)d_in[0];
  const int* ii = (const int*)d_in[1];
  const float* f_w = (const float*)d_in[2];
  const float* f_b = (const float*)d_in[3];
  const float* g_w = (const float*)d_in[4];
  const float* g_b = (const float*)d_in[5];
  const float* h_w = (const float*)d_in[6];
  const float* h_b = (const float*)d_in[7];
  float* out = (float*)d_out;

  char* ws = (char*)d_ws;
  size_t off = 0;
  auto alloc = [&](size_t bytes) {
    size_t p = off;
    off = (off + bytes + 255) & ~(size_t)255;
    return p;
  };
  unsigned short* wt2 = (unsigned short*)(ws + alloc((size_t)NC * D * 2));
  unsigned short* hw = (unsigned short*)(ws + alloc((size_t)D * D * 2));
  float* s1acc = (float*)(ws + alloc((size_t)BATCH * MG * D * 4)); // 3 MB
  float* s2acc = (float*)(ws + alloc((size_t)BATCH * MG * D * 4)); // contiguous after s1acc
  float* outpre = (float*)(ws + alloc((size_t)BATCH * MG * D * 4));
  int* csr_rows = (int*)(ws + alloc((size_t)NROWS * 4));
  int* grp_sorted = (int*)(ws + alloc((size_t)NROWS * 4));

  k_prep<<<dim3(128), dim3(512), 0, stream>>>(ii, g_w, f_w, h_w, wt2, hw, csr_rows,
                                              grp_sorted, s1acc);
  k_gemm1<<<dim3(1024), dim3(256), 0, stream>>>(x, wt2, g_b, f_b, csr_rows, grp_sorted,
                                                s1acc, s2acc);
  k_gemm2<<<dim3(D / 64, (BATCH * MG) / 16), dim3(256), 0, stream>>>(s1acc, s2acc, hw, h_b,
                                                                     outpre);
  k_gather<<<dim3(4096), dim3(256), 0, stream>>>(outpre, ii, out);
}

// Round 13
// 198.947 us; speedup vs baseline: 1.1624x; 1.1624x over previous
//
#include <hip/hip_runtime.h>
#include <hip/hip_bf16.h>

#define D 384
#define NROWS 16384
#define BATCH 4
#define MG 512
#define RTOT (BATCH * NROWS) /* 65536 */
#define NC (2 * D)           /* 768 combined B rows: g|f panels per j-block */
#define JB 64                /* j-columns per panel */
#define NJB (D / JB)         /* 6 */
#define NKT 12               /* K-steps of 32 */

typedef __attribute__((ext_vector_type(8))) short bf16x8;
typedef __attribute__((ext_vector_type(4))) float f32x4;

static __device__ __forceinline__ unsigned short f2bf(float f) {
  unsigned int u = __float_as_uint(f);
  unsigned int r = u + 0x7fffu + ((u >> 16) & 1u); // RNE
  return (unsigned short)(r >> 16);
}
static __device__ __forceinline__ unsigned int cvtpk(float lo, float hi) {
  unsigned int r;
  asm("v_cvt_pk_bf16_f32 %0, %1, %2" : "=v"(r) : "v"(lo), "v"(hi));
  return r;
}
static __device__ __forceinline__ float frcp(float f) {
  float r;
  asm("v_rcp_f32 %0, %1" : "=v"(r) : "v"(f));
  return r;
}

// ---------------- preprocessing: CSR + zero s12 + weights bf16 ----------------
__global__ __launch_bounds__(512) void k_prep(
    const int* __restrict__ ii, const float* __restrict__ g_w,
    const float* __restrict__ f_w, const float* __restrict__ h_w,
    unsigned short* __restrict__ wt2, unsigned short* __restrict__ hw,
    int* __restrict__ csr_rows, int* __restrict__ grp_sorted,
    float* __restrict__ s12) {
  __shared__ int cnt[MG];
  __shared__ int scan[MG];
  const int blk = blockIdx.x;
  const int t = threadIdx.x; // 512 threads
  if (blk == 0) {
    cnt[t] = 0;
    __syncthreads();
    for (int n = t; n < NROWS; n += MG) atomicAdd(&cnt[ii[n]], 1);
    __syncthreads();
    const int v = cnt[t];
    scan[t] = v;
    __syncthreads();
#pragma unroll
    for (int o = 1; o < MG; o <<= 1) { // Hillis-Steele inclusive scan
      int u = (t >= o) ? scan[t - o] : 0;
      __syncthreads();
      scan[t] += u;
      __syncthreads();
    }
    cnt[t] = scan[t] - v; // exclusive
    __syncthreads();
    for (int n = t; n < NROWS; n += MG) {
      int m = ii[n];
      int pos = atomicAdd(&cnt[m], 1);
      csr_rows[pos] = n;
      grp_sorted[pos] = m;
    }
  } else if (blk < 64) {
    const int tot4 = 2 * BATCH * MG * D / 4;
    float4 z = {0.f, 0.f, 0.f, 0.f};
    for (int i = (blk - 1) * 512 + t; i < tot4; i += 63 * 512) ((float4*)s12)[i] = z;
  } else {
    const int tid0 = (blk - 64) * 512 + t;
    const int stride = 64 * 512;
    for (int idx = tid0; idx < NC * D; idx += stride) {
      int jblk = idx / (128 * D);
      int rem = idx % (128 * D);
      int c = rem / D, k = rem % D;
      int j = jblk * JB + (c & 63);
      float v = (c < JB) ? g_w[j * D + k] : f_w[j * D + k];
      wt2[idx] = f2bf(v);
    }
    for (int idx = tid0; idx < D * D; idx += stride) hw[idx] = f2bf(h_w[idx]);
  }
}

// ---------------- fused GEMM + exp + segment-reduce, barrier-free k-loop ----------------
// Block = 64 CSR rows, 256 threads (4 waves, each = 64 rows x 16 g-cols +
// their 16 paired f-cols => acc[4][2] = 32 VGPR; fits the 128-VGPR budget
// WITHOUT spill -- R11/R12's failure cause). A staged ONCE from f32 x
// (cvt_pk, XOR-swizzled, 48 KB LDS); ONE barrier. B direct global->reg from
// L2-hot wt2 (1.18 MB) with 2-ahead named-register pipeline (b0/b1, 16 VGPR).
// 6 panels sequentially; epilogue per panel. ~3 blocks/CU -> real TLP.
__global__ __launch_bounds__(256) void k_gemm1(
    const float* __restrict__ x, const unsigned short* __restrict__ wt2,
    const float* __restrict__ g_b, const float* __restrict__ f_b,
    const int* __restrict__ csr_rows, const int* __restrict__ grp_sorted,
    float* __restrict__ s1acc, float* __restrict__ s2acc) {
  __shared__ __attribute__((aligned(16))) unsigned short As[NKT * 2048]; // 48 KiB resident
  __shared__ int grpS[64];

  const int tid = threadIdx.x;
  const int lane = tid & 63, wq = tid >> 6; // 4 waves: 16-col slice wq
  const int blk = blockIdx.x;               // 0..1023
  const int b = blk >> 8;                   // batch
  const int ibl = (blk & 255) * 64;

  if (tid < 64) grpS[tid] = grp_sorted[ibl + tid];

  const int swz16 = ((lane >> 4) ^ ((lane >> 1) & 3)) * 16; // swizzled read slot

  // B fragment base pointers: n=0 -> g-col slice (panel rows wq*16..),
  // n=1 -> paired f-col slice (panel rows 64+wq*16..)
  const unsigned short* bP[2];
#pragma unroll
  for (int n = 0; n < 2; n++) {
    const int c = n * 64 + wq * 16;
    bP[n] = wt2 + (size_t)(c + (lane & 15)) * D + (lane >> 4) * 8;
  }

  bf16x8 b0[2], b1[2];

#define LOADB(Bv, jb_, kt_)                                                    \
  _Pragma("unroll") for (int n = 0; n < 2; n++) Bv[n] =                        \
      *(const bf16x8*)(bP[n] + (size_t)(jb_) * (128 * D) + (kt_) * 32);

#define STEPK(kt_, Bv)                                                         \
  _Pragma("unroll") for (int m = 0; m < 4; m++) {                              \
    const bf16x8 af = *(const bf16x8*)((const char*)As + (kt_) * 4096 +        \
        (m * 16 + (lane & 15)) * 64 + swz16);                                  \
    acc[m][0] = __builtin_amdgcn_mfma_f32_16x16x32_bf16(af, Bv[0], acc[m][0], 0, 0, 0); \
    acc[m][1] = __builtin_amdgcn_mfma_f32_16x16x32_bf16(af, Bv[1], acc[m][1], 0, 0, 0); \
  }

  // issue panel-0 B(kt=0) loads first (latency hides under A staging)
  LOADB(b0, 0, 0)

  // ---- stage A once: f32 -> cvt_pk -> swizzled LDS, K-resident ----
  {
    const int arow = tid >> 2; // 0..63
    const int grow = csr_rows[ibl + arow];
    const float* asrc = x + ((size_t)((b << 14) + grow)) * D + (tid & 3) * 8;
    const int aslot = (tid & 3) ^ ((tid >> 3) & 3); // slot ^ ((row>>1)&3)
    char* adst = (char*)As + arow * 64 + aslot * 16;
#pragma unroll
    for (int kt = 0; kt < NKT; ++kt) {
      const float4 v0 = *(const float4*)(asrc + kt * 32);
      const float4 v1 = *(const float4*)(asrc + kt * 32 + 4);
      int4 o;
      o.x = cvtpk(v0.x, v0.y);
      o.y = cvtpk(v0.z, v0.w);
      o.z = cvtpk(v1.x, v1.y);
      o.w = cvtpk(v1.z, v1.w);
      *(int4*)(adst + kt * 4096) = o;
    }
  }
  __syncthreads(); // the ONLY barrier: A (and grpS) visible to all waves

  f32x4 acc[4][2];
#pragma unroll
  for (int m = 0; m < 4; m++) {
    acc[m][0] = (f32x4){0.f, 0.f, 0.f, 0.f};
    acc[m][1] = (f32x4){0.f, 0.f, 0.f, 0.f};
  }

#pragma unroll 1
  for (int jb = 0; jb < 6; ++jb) { // panel loop
#pragma unroll
    for (int k2 = 0; k2 < 6; ++k2) {
      const int kt = 2 * k2;
      LOADB(b1, jb, kt + 1)
      __builtin_amdgcn_s_setprio(1);
      STEPK(kt, b0)
      __builtin_amdgcn_s_setprio(0);
      if (kt + 2 < NKT) {
        LOADB(b0, jb, kt + 2)
      } else if (jb < 5) {
        LOADB(b0, jb + 1, 0) // prefetch next panel's first B under STEP(11)+epilogue
      }
      __builtin_amdgcn_s_setprio(1);
      STEPK(kt + 1, b1)
      __builtin_amdgcn_s_setprio(0);
    }

    // ---- epilogue for panel jb: exp/bias + per-group reduce ----
    {
      const int jA = jb * JB + wq * 16 + (lane & 15);
      const float gb = g_b[jA];
      const float fb = f_b[jA];

      int gmr[4][4];
#pragma unroll
      for (int m = 0; m < 4; m++)
#pragma unroll
        for (int r = 0; r < 4; r++)
          gmr[m][r] = grpS[m * 16 + (lane >> 4) * 4 + r];

#pragma unroll
      for (int m = 0; m < 4; m++)
#pragma unroll
        for (int r = 0; r < 4; r++) {
          const float e0 = expf(acc[m][0][r] + gb);
          const float f0 = acc[m][1][r] + fb;
          acc[m][0][r] = e0;
          acc[m][1][r] = f0 * e0;
        }

      const int gLo = grpS[0], gHi = grpS[63];
      for (int g = gLo; g <= gHi; ++g) {
        float v0 = 0.f, v2 = 0.f;
#pragma unroll
        for (int m = 0; m < 4; m++)
#pragma unroll
          for (int r = 0; r < 4; r++)
            if (gmr[m][r] == g) {
              v0 += acc[m][0][r];
              v2 += acc[m][1][r];
            }
        v0 += __shfl_xor(v0, 16); v0 += __shfl_xor(v0, 32);
        v2 += __shfl_xor(v2, 16); v2 += __shfl_xor(v2, 32);
        if (lane < 16) {
          const size_t o = ((size_t)(b * MG + g)) * D + jb * JB + wq * 16 + lane;
          atomicAdd(s1acc + o, v0);
          atomicAdd(s2acc + o, v2);
        }
      }
      // reset accumulators for next panel
#pragma unroll
      for (int m = 0; m < 4; m++) {
        acc[m][0] = (f32x4){0.f, 0.f, 0.f, 0.f};
        acc[m][1] = (f32x4){0.f, 0.f, 0.f, 0.f};
      }
    }
  }
#undef LOADB
#undef STEPK
}

// ---------------- small GEMM with fused normalize ----------------
__global__ __launch_bounds__(256) void k_gemm2(
    const float* __restrict__ s1, const float* __restrict__ s2,
    const unsigned short* __restrict__ hw, const float* __restrict__ h_b,
    float* __restrict__ outpre) {
  const int tid = threadIdx.x, lane = tid & 63, wid = tid >> 6;
  const int r0 = blockIdx.y * 16;
  const int c0 = blockIdx.x * 64 + wid * 16;
  f32x4 acc = (f32x4){0.f, 0.f, 0.f, 0.f};
  const int arow = r0 + (lane & 15);
  const float* s1p = s1 + (size_t)arow * D + (lane >> 4) * 8;
  const float* s2p = s2 + (size_t)arow * D + (lane >> 4) * 8;
  const unsigned short* bRow = hw + (size_t)(c0 + (lane & 15)) * D + (lane >> 4) * 8;
#pragma unroll
  for (int kt = 0; kt < D / 32; kt++) {
    float4 u0 = *(const float4*)(s1p + kt * 32);
    float4 u1 = *(const float4*)(s1p + kt * 32 + 4);
    float4 w0 = *(const float4*)(s2p + kt * 32);
    float4 w1 = *(const float4*)(s2p + kt * 32 + 4);
    int4 yi;
    yi.x = cvtpk(w0.x * frcp(u0.x + 1e-6f), w0.y * frcp(u0.y + 1e-6f));
    yi.y = cvtpk(w0.z * frcp(u0.z + 1e-6f), w0.w * frcp(u0.w + 1e-6f));
    yi.z = cvtpk(w1.x * frcp(u1.x + 1e-6f), w1.y * frcp(u1.y + 1e-6f));
    yi.w = cvtpk(w1.z * frcp(u1.z + 1e-6f), w1.w * frcp(u1.w + 1e-6f));
    bf16x8 af = *(bf16x8*)&yi;
    bf16x8 bf_ = *(const bf16x8*)(bRow + kt * 32);
    acc = __builtin_amdgcn_mfma_f32_16x16x32_bf16(af, bf_, acc, 0, 0, 0);
  }
  const int col = c0 + (lane & 15);
  const float hb = h_b[col];
#pragma unroll
  for (int r = 0; r < 4; r++) {
    const int row = r0 + (lane >> 4) * 4 + r;
    outpre[(size_t)row * D + col] = acc[r] + hb;
  }
}

// ---------------- gather rows ----------------
__global__ void k_gather(const float* __restrict__ outpre, const int* __restrict__ ii,
                         float* __restrict__ out) {
  const long total4 = (long)RTOT * (D / 4); // 96 float4 per row
  for (long i = blockIdx.x * (long)blockDim.x + threadIdx.x; i < total4;
       i += (long)gridDim.x * blockDim.x) {
    const long row = i / (D / 4);
    const int q = (int)(i % (D / 4));
    const int b = (int)(row >> 14);
    const int n = (int)(row & (NROWS - 1));
    const int g = ii[n];
    ((float4*)out)[i] = ((const float4*)outpre)[((size_t)(b * MG + g)) * (D / 4) + q];
  }
}

extern "C" void kernel_launch(void* const* d_in, const int* in_sizes, int n_in,
                              void* d_out, int out_size, void* d_ws, size_t ws_size,
                              hipStream_t stream) {
  const float* x = (const float*)d_in[0];
  const int* ii = (const int*)d_in[1];
  const float* f_w = (const float*)d_in[2];
  const float* f_b = (const float*)d_in[3];
  const float* g_w = (const float*)d_in[4];
  const float* g_b = (const float*)d_in[5];
  const float* h_w = (const float*)d_in[6];
  const float* h_b = (const float*)d_in[7];
  float* out = (float*)d_out;

  char* ws = (char*)d_ws;
  size_t off = 0;
  auto alloc = [&](size_t bytes) {
    size_t p = off;
    off = (off + bytes + 255) & ~(size_t)255;
    return p;
  };
  unsigned short* wt2 = (unsigned short*)(ws + alloc((size_t)NC * D * 2));
  unsigned short* hw = (unsigned short*)(ws + alloc((size_t)D * D * 2));
  float* s1acc = (float*)(ws + alloc((size_t)BATCH * MG * D * 4)); // 3 MB
  float* s2acc = (float*)(ws + alloc((size_t)BATCH * MG * D * 4)); // contiguous after s1acc
  float* outpre = (float*)(ws + alloc((size_t)BATCH * MG * D * 4));
  int* csr_rows = (int*)(ws + alloc((size_t)NROWS * 4));
  int* grp_sorted = (int*)(ws + alloc((size_t)NROWS * 4));

  k_prep<<<dim3(128), dim3(512), 0, stream>>>(ii, g_w, f_w, h_w, wt2, hw, csr_rows,
                                              grp_sorted, s1acc);
  k_gemm1<<<dim3(1024), dim3(256), 0, stream>>>(x, wt2, g_b, f_b, csr_rows, grp_sorted,
                                                s1acc, s2acc);
  k_gemm2<<<dim3(D / 64, (BATCH * MG) / 16), dim3(256), 0, stream>>>(s1acc, s2acc, hw, h_b,
                                                                     outpre);
  k_gather<<<dim3(4096), dim3(256), 0, stream>>>(outpre, ii, out);
}

// Round 14
// 166.817 us; speedup vs baseline: 1.3863x; 1.1926x over previous
//
#include <hip/hip_runtime.h>
#include <hip/hip_bf16.h>

#define D 384
#define NROWS 16384
#define BATCH 4
#define MG 512
#define RTOT (BATCH * NROWS) /* 65536 */
#define NC (2 * D)           /* 768 combined B rows: g|f panels per j-block */
#define JB 64                /* j-columns per panel */
#define NJB (D / JB)         /* 6 */
#define NKT 12               /* K-steps of 32 */

typedef __attribute__((ext_vector_type(8))) short bf16x8;
typedef __attribute__((ext_vector_type(4))) float f32x4;

static __device__ __forceinline__ unsigned short f2bf(float f) {
  unsigned int u = __float_as_uint(f);
  unsigned int r = u + 0x7fffu + ((u >> 16) & 1u); // RNE
  return (unsigned short)(r >> 16);
}
static __device__ __forceinline__ unsigned int cvtpk(float lo, float hi) {
  unsigned int r;
  asm("v_cvt_pk_bf16_f32 %0, %1, %2" : "=v"(r) : "v"(lo), "v"(hi));
  return r;
}
static __device__ __forceinline__ float frcp(float f) {
  float r;
  asm("v_rcp_f32 %0, %1" : "=v"(r) : "v"(f));
  return r;
}

typedef __attribute__((address_space(1))) const void gvoid_t;
typedef __attribute__((address_space(3))) void lvoid_t;
static __device__ __forceinline__ void gl16(const void* g, void* l) {
  __builtin_amdgcn_global_load_lds((gvoid_t*)g, (lvoid_t*)l, 16, 0, 0);
}

// ---------------- preprocessing: CSR + zero s12 + weights bf16 ----------------
__global__ __launch_bounds__(512) void k_prep(
    const int* __restrict__ ii, const float* __restrict__ g_w,
    const float* __restrict__ f_w, const float* __restrict__ h_w,
    unsigned short* __restrict__ wt2, unsigned short* __restrict__ hw,
    int* __restrict__ csr_rows, int* __restrict__ grp_sorted,
    float* __restrict__ s12) {
  __shared__ int cnt[MG];
  __shared__ int scan[MG];
  const int blk = blockIdx.x;
  const int t = threadIdx.x; // 512 threads
  if (blk == 0) {
    cnt[t] = 0;
    __syncthreads();
    for (int n = t; n < NROWS; n += MG) atomicAdd(&cnt[ii[n]], 1);
    __syncthreads();
    const int v = cnt[t];
    scan[t] = v;
    __syncthreads();
#pragma unroll
    for (int o = 1; o < MG; o <<= 1) { // Hillis-Steele inclusive scan
      int u = (t >= o) ? scan[t - o] : 0;
      __syncthreads();
      scan[t] += u;
      __syncthreads();
    }
    cnt[t] = scan[t] - v; // exclusive
    __syncthreads();
    for (int n = t; n < NROWS; n += MG) {
      int m = ii[n];
      int pos = atomicAdd(&cnt[m], 1);
      csr_rows[pos] = n;
      grp_sorted[pos] = m;
    }
  } else if (blk < 64) {
    const int tot4 = 2 * BATCH * MG * D / 4;
    float4 z = {0.f, 0.f, 0.f, 0.f};
    for (int i = (blk - 1) * 512 + t; i < tot4; i += 63 * 512) ((float4*)s12)[i] = z;
  } else {
    const int tid0 = (blk - 64) * 512 + t;
    const int stride = 64 * 512;
    for (int idx = tid0; idx < NC * D; idx += stride) {
      int jblk = idx / (128 * D);
      int rem = idx % (128 * D);
      int c = rem / D, k = rem % D;
      int j = jblk * JB + (c & 63);
      float v = (c < JB) ? g_w[j * D + k] : f_w[j * D + k];
      wt2[idx] = f2bf(v);
    }
    for (int idx = tid0; idx < D * D; idx += stride) hw[idx] = f2bf(h_w[idx]);
  }
}

// ---------------- fused GEMM + exp + segment-reduce ----------------
// Block = 64 CSR rows, 256 threads (4 waves; wave = 64 rows x {16 g-cols +
// paired 16 f-cols}, acc[4][2] = 32 VGPR, spill-free per R13). A staged ONCE
// from f32 x (cvt_pk, XOR-swizzled, 48 KB LDS). B via LDS TRIPLE-buffer
// (3 x 8 KB): gl16 issued 2 steps ahead, per-step counted s_waitcnt vmcnt(2)
// (R10-proven scheme) -- full drain only on the very last step. 72 steps.
// LDS 72.4 KB -> 2 blocks/CU: cross-block overlap fills barrier skew.
__global__ __launch_bounds__(256) void k_gemm1(
    const float* __restrict__ x, const unsigned short* __restrict__ wt2,
    const float* __restrict__ g_b, const float* __restrict__ f_b,
    const int* __restrict__ csr_rows, const int* __restrict__ grp_sorted,
    float* __restrict__ s1acc, float* __restrict__ s2acc) {
  __shared__ __attribute__((aligned(16))) unsigned short As[NKT * 2048]; // 48 KiB resident
  __shared__ __attribute__((aligned(16))) unsigned short Bs[3][4096];    // 3 x 8 KiB
  __shared__ int grpS[64];

  const int tid = threadIdx.x;
  const int lane = tid & 63, wq = tid >> 6; // 4 waves: 16-col slice wq
  const int blk = blockIdx.x;               // 0..1023
  const int b = blk >> 8;                   // batch
  const int ibl = (blk & 255) * 64;

  if (tid < 64) grpS[tid] = grp_sorted[ibl + tid];

  const int skb = ((lane & 3) ^ ((lane >> 3) & 3)) * 16;    // staging source swizzle
  const int swz16 = ((lane >> 4) ^ ((lane >> 1) & 3)) * 16; // swizzled read slot

  // B staging: wave wq covers panel rows wq*32..+31 as two 16-row calls.
  const char* wtb = (const char*)wt2;
  const int prow0 = wq * 32 + (lane >> 2);
  const size_t bso0 = (size_t)prow0 * (D * 2) + skb;
  const size_t bso1 = (size_t)(prow0 + 16) * (D * 2) + skb;

  // prologue: issue B(step 0)=[jb0,kt0] into buf0 and B(step 1)=[jb0,kt1] into buf1
  {
    char* d0 = (char*)&Bs[0][0] + wq * 2048;
    gl16(wtb + bso0, d0);
    gl16(wtb + bso1, d0 + 1024);
    char* d1 = (char*)&Bs[1][0] + wq * 2048;
    gl16(wtb + bso0 + 64, d1);
    gl16(wtb + bso1 + 64, d1 + 1024);
  }

  // ---- stage A once: f32 -> cvt_pk -> swizzled LDS, K-resident ----
  {
    const int arow = tid >> 2; // 0..63
    const int grow = csr_rows[ibl + arow];
    const float* asrc = x + ((size_t)((b << 14) + grow)) * D + (tid & 3) * 8;
    const int aslot = (tid & 3) ^ ((tid >> 3) & 3); // slot ^ ((row>>1)&3)
    char* adst = (char*)As + arow * 64 + aslot * 16;
#pragma unroll
    for (int kt = 0; kt < NKT; ++kt) {
      const float4 v0 = *(const float4*)(asrc + kt * 32);
      const float4 v1 = *(const float4*)(asrc + kt * 32 + 4);
      int4 o;
      o.x = cvtpk(v0.x, v0.y);
      o.y = cvtpk(v0.z, v0.w);
      o.z = cvtpk(v1.x, v1.y);
      o.w = cvtpk(v1.z, v1.w);
      *(int4*)(adst + kt * 4096) = o;
    }
  }
  __syncthreads(); // A + grpS visible; B(0)/B(1) still possibly in flight

  f32x4 acc[4][2];
#pragma unroll
  for (int m = 0; m < 4; m++) {
    acc[m][0] = (f32x4){0.f, 0.f, 0.f, 0.f};
    acc[m][1] = (f32x4){0.f, 0.f, 0.f, 0.f};
  }

#pragma unroll 1
  for (int jb = 0; jb < 6; ++jb) { // panel loop
#pragma unroll
    for (int kt = 0; kt < NKT; ++kt) {
      // counted wait: B(s) landed; B(s+1),B(s+2) may stay in flight.
      // Only the final step of the kernel needs a full drain.
      if (jb == 5 && kt == 11)
        asm volatile("s_waitcnt vmcnt(0)\ns_barrier" ::: "memory");
      else
        asm volatile("s_waitcnt vmcnt(2)\ns_barrier" ::: "memory");
      // issue B(s+2) into buf (kt+2)%3 (its readers finished before the
      // barrier above; 12%3==0 keeps buffer index jb-invariant)
      if (!(jb == 5 && kt >= 10)) {
        const int kt2 = (kt + 2) % 12;
        const int jb2 = jb + (kt + 2) / 12;
        char* nd = (char*)&Bs[(kt + 2) % 3][0] + wq * 2048;
        gl16(wtb + (size_t)jb2 * (128 * D * 2) + bso0 + kt2 * 64, nd);
        gl16(wtb + (size_t)jb2 * (128 * D * 2) + bso1 + kt2 * 64, nd + 1024);
      }
      // fragments: A from resident As[kt], B from Bs[kt%3]
      const char* bb = (const char*)&Bs[kt % 3][0];
      const bf16x8 bg = *(const bf16x8*)(bb + (wq * 16 + (lane & 15)) * 64 + swz16);
      const bf16x8 bf_ = *(const bf16x8*)(bb + (64 + wq * 16 + (lane & 15)) * 64 + swz16);
      __builtin_amdgcn_s_setprio(1);
#pragma unroll
      for (int m = 0; m < 4; m++) {
        const bf16x8 af = *(const bf16x8*)((const char*)As + kt * 4096 +
                                           (m * 16 + (lane & 15)) * 64 + swz16);
        acc[m][0] = __builtin_amdgcn_mfma_f32_16x16x32_bf16(af, bg, acc[m][0], 0, 0, 0);
        acc[m][1] = __builtin_amdgcn_mfma_f32_16x16x32_bf16(af, bf_, acc[m][1], 0, 0, 0);
      }
      __builtin_amdgcn_s_setprio(0);
    }

    // ---- epilogue for panel jb: exp/bias + per-group reduce ----
    {
      const int jA = jb * JB + wq * 16 + (lane & 15);
      const float gb = g_b[jA];
      const float fb = f_b[jA];

      int gmr[4][4];
#pragma unroll
      for (int m = 0; m < 4; m++)
#pragma unroll
        for (int r = 0; r < 4; r++)
          gmr[m][r] = grpS[m * 16 + (lane >> 4) * 4 + r];

#pragma unroll
      for (int m = 0; m < 4; m++)
#pragma unroll
        for (int r = 0; r < 4; r++) {
          const float e0 = expf(acc[m][0][r] + gb);
          const float f0 = acc[m][1][r] + fb;
          acc[m][0][r] = e0;
          acc[m][1][r] = f0 * e0;
        }

      const int gLo = grpS[0], gHi = grpS[63];
      for (int g = gLo; g <= gHi; ++g) {
        float v0 = 0.f, v2 = 0.f;
#pragma unroll
        for (int m = 0; m < 4; m++)
#pragma unroll
          for (int r = 0; r < 4; r++)
            if (gmr[m][r] == g) {
              v0 += acc[m][0][r];
              v2 += acc[m][1][r];
            }
        v0 += __shfl_xor(v0, 16); v0 += __shfl_xor(v0, 32);
        v2 += __shfl_xor(v2, 16); v2 += __shfl_xor(v2, 32);
        if (lane < 16) {
          const size_t o = ((size_t)(b * MG + g)) * D + jb * JB + wq * 16 + lane;
          atomicAdd(s1acc + o, v0);
          atomicAdd(s2acc + o, v2);
        }
      }
      // reset accumulators for next panel
#pragma unroll
      for (int m = 0; m < 4; m++) {
        acc[m][0] = (f32x4){0.f, 0.f, 0.f, 0.f};
        acc[m][1] = (f32x4){0.f, 0.f, 0.f, 0.f};
      }
    }
  }
}

// ---------------- small GEMM with fused normalize ----------------
__global__ __launch_bounds__(256) void k_gemm2(
    const float* __restrict__ s1, const float* __restrict__ s2,
    const unsigned short* __restrict__ hw, const float* __restrict__ h_b,
    float* __restrict__ outpre) {
  const int tid = threadIdx.x, lane = tid & 63, wid = tid >> 6;
  const int r0 = blockIdx.y * 16;
  const int c0 = blockIdx.x * 64 + wid * 16;
  f32x4 acc = (f32x4){0.f, 0.f, 0.f, 0.f};
  const int arow = r0 + (lane & 15);
  const float* s1p = s1 + (size_t)arow * D + (lane >> 4) * 8;
  const float* s2p = s2 + (size_t)arow * D + (lane >> 4) * 8;
  const unsigned short* bRow = hw + (size_t)(c0 + (lane & 15)) * D + (lane >> 4) * 8;
#pragma unroll
  for (int kt = 0; kt < D / 32; kt++) {
    float4 u0 = *(const float4*)(s1p + kt * 32);
    float4 u1 = *(const float4*)(s1p + kt * 32 + 4);
    float4 w0 = *(const float4*)(s2p + kt * 32);
    float4 w1 = *(const float4*)(s2p + kt * 32 + 4);
    int4 yi;
    yi.x = cvtpk(w0.x * frcp(u0.x + 1e-6f), w0.y * frcp(u0.y + 1e-6f));
    yi.y = cvtpk(w0.z * frcp(u0.z + 1e-6f), w0.w * frcp(u0.w + 1e-6f));
    yi.z = cvtpk(w1.x * frcp(u1.x + 1e-6f), w1.y * frcp(u1.y + 1e-6f));
    yi.w = cvtpk(w1.z * frcp(u1.z + 1e-6f), w1.w * frcp(u1.w + 1e-6f));
    bf16x8 af = *(bf16x8*)&yi;
    bf16x8 bf_ = *(const bf16x8*)(bRow + kt * 32);
    acc = __builtin_amdgcn_mfma_f32_16x16x32_bf16(af, bf_, acc, 0, 0, 0);
  }
  const int col = c0 + (lane & 15);
  const float hb = h_b[col];
#pragma unroll
  for (int r = 0; r < 4; r++) {
    const int row = r0 + (lane >> 4) * 4 + r;
    outpre[(size_t)row * D + col] = acc[r] + hb;
  }
}

// ---------------- gather rows ----------------
__global__ void k_gather(const float* __restrict__ outpre, const int* __restrict__ ii,
                         float* __restrict__ out) {
  const long total4 = (long)RTOT * (D / 4); // 96 float4 per row
  for (long i = blockIdx.x * (long)blockDim.x + threadIdx.x; i < total4;
       i += (long)gridDim.x * blockDim.x) {
    const long row = i / (D / 4);
    const int q = (int)(i % (D / 4));
    const int b = (int)(row >> 14);
    const int n = (int)(row & (NROWS - 1));
    const int g = ii[n];
    ((float4*)out)[i] = ((const float4*)outpre)[((size_t)(b * MG + g)) * (D / 4) + q];
  }
}

extern "C" void kernel_launch(void* const* d_in, const int* in_sizes, int n_in,
                              void* d_out, int out_size, void* d_ws, size_t ws_size,
                              hipStream_t stream) {
  const float* x = (const float*)d_in[0];
  const int* ii = (const int*)d_in[1];
  const float* f_w = (const float*)d_in[2];
  const float* f_b = (const float*)d_in[3];
  const float* g_w = (const float*)d_in[4];
  const float* g_b = (const float*)d_in[5];
  const float* h_w = (const float*)d_in[6];
  const float* h_b = (const float*)d_in[7];
  float* out = (float*)d_out;

  char* ws = (char*)d_ws;
  size_t off = 0;
  auto alloc = [&](size_t bytes) {
    size_t p = off;
    off = (off + bytes + 255) & ~(size_t)255;
    return p;
  };
  unsigned short* wt2 = (unsigned short*)(ws + alloc((size_t)NC * D * 2));
  unsigned short* hw = (unsigned short*)(ws + alloc((size_t)D * D * 2));
  float* s1acc = (float*)(ws + alloc((size_t)BATCH * MG * D * 4)); // 3 MB
  float* s2acc = (float*)(ws + alloc((size_t)BATCH * MG * D * 4)); // contiguous after s1acc
  float* outpre = (float*)(ws + alloc((size_t)BATCH * MG * D * 4));
  int* csr_rows = (int*)(ws + alloc((size_t)NROWS * 4));
  int* grp_sorted = (int*)(ws + alloc((size_t)NROWS * 4));

  k_prep<<<dim3(128), dim3(512), 0, stream>>>(ii, g_w, f_w, h_w, wt2, hw, csr_rows,
                                              grp_sorted, s1acc);
  k_gemm1<<<dim3(1024), dim3(256), 0, stream>>>(x, wt2, g_b, f_b, csr_rows, grp_sorted,
                                                s1acc, s2acc);
  k_gemm2<<<dim3(D / 64, (BATCH * MG) / 16), dim3(256), 0, stream>>>(s1acc, s2acc, hw, h_b,
                                                                     outpre);
  k_gather<<<dim3(4096), dim3(256), 0, stream>>>(outpre, ii, out);
}

// Round 15
// 136.649 us; speedup vs baseline: 1.6923x; 1.2208x over previous
//
#include <hip/hip_runtime.h>
#include <hip/hip_bf16.h>

#define D 384
#define NROWS 16384
#define BATCH 4
#define MG 512
#define RTOT (BATCH * NROWS) /* 65536 */
#define NC (2 * D)           /* 768 combined B rows: g|f panels per j-block */
#define JB 64                /* j-columns per panel */
#define NJB (D / JB)         /* 6 */
#define NKT 12               /* K-steps of 32 */

typedef __attribute__((ext_vector_type(8))) short bf16x8;
typedef __attribute__((ext_vector_type(4))) float f32x4;

static __device__ __forceinline__ unsigned short f2bf(float f) {
  unsigned int u = __float_as_uint(f);
  unsigned int r = u + 0x7fffu + ((u >> 16) & 1u); // RNE
  return (unsigned short)(r >> 16);
}
static __device__ __forceinline__ unsigned int cvtpk(float lo, float hi) {
  unsigned int r;
  asm("v_cvt_pk_bf16_f32 %0, %1, %2" : "=v"(r) : "v"(lo), "v"(hi));
  return r;
}
static __device__ __forceinline__ float frcp(float f) {
  float r;
  asm("v_rcp_f32 %0, %1" : "=v"(r) : "v"(f));
  return r;
}

typedef __attribute__((address_space(1))) const void gvoid_t;
typedef __attribute__((address_space(3))) void lvoid_t;
static __device__ __forceinline__ void gl16(const void* g, void* l) {
  __builtin_amdgcn_global_load_lds((gvoid_t*)g, (lvoid_t*)l, 16, 0, 0);
}

// ---------------- preprocessing: CSR + zero s12 + weights bf16 (1024 thr) ----------------
__global__ __launch_bounds__(1024) void k_prep(
    const int* __restrict__ ii, const float* __restrict__ g_w,
    const float* __restrict__ f_w, const float* __restrict__ h_w,
    unsigned short* __restrict__ wt2, unsigned short* __restrict__ hw,
    int* __restrict__ csr_rows, int* __restrict__ grp_sorted,
    float* __restrict__ s12) {
  __shared__ int cnt[MG];
  __shared__ int scan[MG];
  const int blk = blockIdx.x;
  const int t = threadIdx.x; // 1024 threads
  if (blk == 0) {
    if (t < MG) cnt[t] = 0;
    __syncthreads();
    for (int n = t; n < NROWS; n += 1024) atomicAdd(&cnt[ii[n]], 1);
    __syncthreads();
    const int v = (t < MG) ? cnt[t] : 0;
    if (t < MG) scan[t] = v;
    __syncthreads();
#pragma unroll
    for (int o = 1; o < MG; o <<= 1) { // Hillis-Steele inclusive scan
      int u2 = (t >= o && t < MG) ? scan[t - o] : 0;
      __syncthreads();
      if (t < MG) scan[t] += u2;
      __syncthreads();
    }
    if (t < MG) cnt[t] = scan[t] - v; // exclusive
    __syncthreads();
    for (int n = t; n < NROWS; n += 1024) {
      int m = ii[n];
      int pos = atomicAdd(&cnt[m], 1);
      csr_rows[pos] = n;
      grp_sorted[pos] = m;
    }
  } else if (blk < 32) {
    const int tot4 = 2 * BATCH * MG * D / 4; // 786432 float4
    float4 z = {0.f, 0.f, 0.f, 0.f};
    for (int i = (blk - 1) * 1024 + t; i < tot4; i += 31 * 1024) ((float4*)s12)[i] = z;
  } else {
    const int tid0 = (blk - 32) * 1024 + t;
    const int stride = 64 * 1024;
    for (int idx = tid0; idx < NC * D; idx += stride) {
      int jblk = idx / (128 * D);
      int rem = idx % (128 * D);
      int c = rem / D, k = rem % D;
      int j = jblk * JB + (c & 63);
      float v = (c < JB) ? g_w[j * D + k] : f_w[j * D + k];
      wt2[idx] = f2bf(v);
    }
    for (int idx = tid0; idx < D * D; idx += stride) hw[idx] = f2bf(h_w[idx]);
  }
}

// ---------------- fused GEMM + exp + segment-reduce (Round-10 measured-best) ----------------
// Block = one 128-row CSR group (A block-constant). A staged ONCE from f32 x
// (reg-stage + cvt_pk), K-resident in LDS 96 KB (XOR-swizzled). B TRIPLE-
// buffered (48 KB): gl16 issued 2 steps ahead; per-step wait is counted
// s_waitcnt vmcnt(2) -- full drain only on the true final step (race fix).
__global__ __launch_bounds__(512, 1) void k_gemm1(
    const float* __restrict__ x, const unsigned short* __restrict__ wt2,
    const float* __restrict__ g_b, const float* __restrict__ f_b,
    const int* __restrict__ csr_rows, const int* __restrict__ grp_sorted,
    float* __restrict__ s1acc, float* __restrict__ s2acc) {
  __shared__ __attribute__((aligned(16))) unsigned short As[NKT * 4096]; // 96 KiB resident
  __shared__ __attribute__((aligned(16))) unsigned short Bs[3][2][4096]; // 48 KiB triple-buf
  __shared__ int grpS[128];

  const int tid = threadIdx.x;
  const int lane = tid & 63, wid = tid >> 6;
  const int wr = wid >> 2;    // m-group (64 rows)
  const int wq = wid & 3;
  const int p = wq >> 1;      // panel within item
  const int u = wq & 1;       // 32-j half within panel
  const int blk = blockIdx.x; // 0..511
  const int b = blk >> 7;     // batch
  const int ibl = (blk & 127) * 128;

  if (tid < 128) grpS[tid] = grp_sorted[ibl + tid];

  const int skb = ((lane & 3) ^ ((lane >> 3) & 3)) * 16;    // swizzled source chunk
  const int swz16 = ((lane >> 4) ^ ((lane >> 1) & 3)) * 16; // swizzled read slot

  // ---- issue B(step 0) and B(step 1): item 0 panels 0,1, kt=0 and kt=1 ----
  const char* wtb = (const char*)wt2;
  const int prow = wid * 16 + (lane >> 2); // row within panel
  const size_t bsrcoff = (size_t)prow * (D * 2) + skb;
  {
    char* b0 = (char*)&Bs[0][0][0] + wid * 1024;
    char* b1 = (char*)&Bs[1][0][0] + wid * 1024;
    gl16(wtb + 0 * (128 * D * 2) + 0 * 64 + bsrcoff, b0);
    gl16(wtb + 1 * (128 * D * 2) + 0 * 64 + bsrcoff, b0 + 8192);
    gl16(wtb + 0 * (128 * D * 2) + 1 * 64 + bsrcoff, b1);
    gl16(wtb + 1 * (128 * D * 2) + 1 * 64 + bsrcoff, b1 + 8192);
  }

  // ---- stage A once: f32 gather -> cvt_pk -> swizzled LDS, K-resident ----
  {
    const int arow = tid >> 2; // 0..127
    const int grow = csr_rows[ibl + arow];
    const float* asrc = x + ((size_t)((b << 14) + grow)) * D + (tid & 3) * 8;
    const int aslot = (tid & 3) ^ ((tid >> 3) & 3);
    char* adst = (char*)As + arow * 64 + aslot * 16;
#pragma unroll
    for (int kt = 0; kt < NKT; ++kt) {
      const float4 v0 = *(const float4*)(asrc + kt * 32);
      const float4 v1 = *(const float4*)(asrc + kt * 32 + 4);
      int4 o;
      o.x = cvtpk(v0.x, v0.y);
      o.y = cvtpk(v0.z, v0.w);
      o.z = cvtpk(v1.x, v1.y);
      o.w = cvtpk(v1.z, v1.w);
      *(int4*)(adst + kt * 8192) = o;
    }
  }
  __syncthreads(); // drains lgkm (A writes); B(0),B(1) may remain in flight

  f32x4 acc[4][4];
#pragma unroll
  for (int m = 0; m < 4; m++)
#pragma unroll
    for (int n = 0; n < 4; n++) acc[m][n] = (f32x4){0.f, 0.f, 0.f, 0.f};

#pragma unroll 1
  for (int e = 0; e < 3; ++e) {
#pragma unroll
    for (int kt = 0; kt < NKT; ++kt) {
      // counted wait: B(s) landed; B(s+1),B(s+2) may remain in flight.
      // Final step must fully drain (only B(35) outstanding there).
      if (e == 2 && kt == 11)
        asm volatile("s_waitcnt vmcnt(0)\ns_barrier" ::: "memory");
      else
        asm volatile("s_waitcnt vmcnt(2)\ns_barrier" ::: "memory");
      // issue B(s+2) into buffer (kt+2)%3 (readers finished pre-barrier;
      // 12%3==0 keeps the buffer index e-invariant)
      if (!(e == 2 && kt >= 10)) {
        const int kt2 = (kt + 2) % 12;
        const int jbn = 2 * (e + (kt + 2) / 12);
        char* nd = (char*)&Bs[(kt + 2) % 3][0][0] + wid * 1024;
        gl16(wtb + (size_t)jbn * (128 * D * 2) + kt2 * 64 + bsrcoff, nd);
        gl16(wtb + (size_t)(jbn + 1) * (128 * D * 2) + kt2 * 64 + bsrcoff, nd + 8192);
      }
      // fragments
      bf16x8 af[4], bfv[4];
      const char* ab = (const char*)As + kt * 8192;
#pragma unroll
      for (int m = 0; m < 4; m++)
        af[m] = *(const bf16x8*)(ab + (wr * 64 + m * 16 + (lane & 15)) * 64 + swz16);
      const char* bb = (const char*)&Bs[kt % 3][p][0];
#pragma unroll
      for (int n = 0; n < 4; n++) {
        const int c = (n < 2) ? (u * 32 + n * 16) : (64 + u * 32 + (n - 2) * 16);
        bfv[n] = *(const bf16x8*)(bb + (c + (lane & 15)) * 64 + swz16);
      }
      __builtin_amdgcn_s_setprio(1);
#pragma unroll
      for (int m = 0; m < 4; m++)
#pragma unroll
        for (int n = 0; n < 4; n++)
          acc[m][n] = __builtin_amdgcn_mfma_f32_16x16x32_bf16(af[m], bfv[n], acc[m][n], 0, 0, 0);
      __builtin_amdgcn_s_setprio(0);
    }

    // ---- epilogue for item e (panels 2e+p): exp/bias + per-group reduce ----
    {
      const int j0 = (2 * e + p) * JB;
      const int jA = j0 + u * 32 + (lane & 15);
      const float gb0 = g_b[jA], gb1 = g_b[jA + 16];
      const float fb0 = f_b[jA], fb1 = f_b[jA + 16];
      const int rowbase = wr * 64;

      int gmr[4][4];
#pragma unroll
      for (int m = 0; m < 4; m++)
#pragma unroll
        for (int r = 0; r < 4; r++)
          gmr[m][r] = grpS[rowbase + m * 16 + (lane >> 4) * 4 + r];

#pragma unroll
      for (int m = 0; m < 4; m++)
#pragma unroll
        for (int r = 0; r < 4; r++) {
          const float e0 = __expf(acc[m][0][r] + gb0);
          const float e1 = __expf(acc[m][1][r] + gb1);
          const float f0 = acc[m][2][r] + fb0;
          const float f1 = acc[m][3][r] + fb1;
          acc[m][0][r] = e0; acc[m][1][r] = e1;
          acc[m][2][r] = f0 * e0; acc[m][3][r] = f1 * e1;
        }

      const int gLo = grpS[rowbase], gHi = grpS[rowbase + 63];
      for (int g = gLo; g <= gHi; ++g) {
        float v0 = 0.f, v1 = 0.f, v2 = 0.f, v3 = 0.f;
#pragma unroll
        for (int m = 0; m < 4; m++)
#pragma unroll
          for (int r = 0; r < 4; r++)
            if (gmr[m][r] == g) {
              v0 += acc[m][0][r]; v1 += acc[m][1][r];
              v2 += acc[m][2][r]; v3 += acc[m][3][r];
            }
        v0 += __shfl_xor(v0, 16); v0 += __shfl_xor(v0, 32);
        v1 += __shfl_xor(v1, 16); v1 += __shfl_xor(v1, 32);
        v2 += __shfl_xor(v2, 16); v2 += __shfl_xor(v2, 32);
        v3 += __shfl_xor(v3, 16); v3 += __shfl_xor(v3, 32);
        if (lane < 16) {
          float* s1p = s1acc + ((size_t)(b * MG + g)) * D + j0 + u * 32 + lane;
          float* s2p = s2acc + ((size_t)(b * MG + g)) * D + j0 + u * 32 + lane;
          atomicAdd(s1p, v0);
          atomicAdd(s1p + 16, v1);
          atomicAdd(s2p, v2);
          atomicAdd(s2p + 16, v3);
        }
      }
    }
    // reset accumulators for next item
#pragma unroll
    for (int m = 0; m < 4; m++)
#pragma unroll
      for (int n = 0; n < 4; n++) acc[m][n] = (f32x4){0.f, 0.f, 0.f, 0.f};
  }
}

// ---------------- small GEMM with fused normalize ----------------
__global__ __launch_bounds__(256) void k_gemm2(
    const float* __restrict__ s1, const float* __restrict__ s2,
    const unsigned short* __restrict__ hw, const float* __restrict__ h_b,
    float* __restrict__ outpre) {
  const int tid = threadIdx.x, lane = tid & 63, wid = tid >> 6;
  const int r0 = blockIdx.y * 16;
  const int c0 = blockIdx.x * 64 + wid * 16;
  f32x4 acc = (f32x4){0.f, 0.f, 0.f, 0.f};
  const int arow = r0 + (lane & 15);
  const float* s1p = s1 + (size_t)arow * D + (lane >> 4) * 8;
  const float* s2p = s2 + (size_t)arow * D + (lane >> 4) * 8;
  const unsigned short* bRow = hw + (size_t)(c0 + (lane & 15)) * D + (lane >> 4) * 8;
#pragma unroll
  for (int kt = 0; kt < D / 32; kt++) {
    float4 u0 = *(const float4*)(s1p + kt * 32);
    float4 u1 = *(const float4*)(s1p + kt * 32 + 4);
    float4 w0 = *(const float4*)(s2p + kt * 32);
    float4 w1 = *(const float4*)(s2p + kt * 32 + 4);
    int4 yi;
    yi.x = cvtpk(w0.x * frcp(u0.x + 1e-6f), w0.y * frcp(u0.y + 1e-6f));
    yi.y = cvtpk(w0.z * frcp(u0.z + 1e-6f), w0.w * frcp(u0.w + 1e-6f));
    yi.z = cvtpk(w1.x * frcp(u1.x + 1e-6f), w1.y * frcp(u1.y + 1e-6f));
    yi.w = cvtpk(w1.z * frcp(u1.z + 1e-6f), w1.w * frcp(u1.w + 1e-6f));
    bf16x8 af = *(bf16x8*)&yi;
    bf16x8 bf_ = *(const bf16x8*)(bRow + kt * 32);
    acc = __builtin_amdgcn_mfma_f32_16x16x32_bf16(af, bf_, acc, 0, 0, 0);
  }
  const int col = c0 + (lane & 15);
  const float hb = h_b[col];
#pragma unroll
  for (int r = 0; r < 4; r++) {
    const int row = r0 + (lane >> 4) * 4 + r;
    outpre[(size_t)row * D + col] = acc[r] + hb;
  }
}

// ---------------- gather rows ----------------
__global__ void k_gather(const float* __restrict__ outpre, const int* __restrict__ ii,
                         float* __restrict__ out) {
  const long total4 = (long)RTOT * (D / 4); // 96 float4 per row
  for (long i = blockIdx.x * (long)blockDim.x + threadIdx.x; i < total4;
       i += (long)gridDim.x * blockDim.x) {
    const long row = i / (D / 4);
    const int q = (int)(i % (D / 4));
    const int b = (int)(row >> 14);
    const int n = (int)(row & (NROWS - 1));
    const int g = ii[n];
    ((float4*)out)[i] = ((const float4*)outpre)[((size_t)(b * MG + g)) * (D / 4) + q];
  }
}

extern "C" void kernel_launch(void* const* d_in, const int* in_sizes, int n_in,
                              void* d_out, int out_size, void* d_ws, size_t ws_size,
                              hipStream_t stream) {
  const float* x = (const float*)d_in[0];
  const int* ii = (const int*)d_in[1];
  const float* f_w = (const float*)d_in[2];
  const float* f_b = (const float*)d_in[3];
  const float* g_w = (const float*)d_in[4];
  const float* g_b = (const float*)d_in[5];
  const float* h_w = (const float*)d_in[6];
  const float* h_b = (const float*)d_in[7];
  float* out = (float*)d_out;

  char* ws = (char*)d_ws;
  size_t off = 0;
  auto alloc = [&](size_t bytes) {
    size_t p = off;
    off = (off + bytes + 255) & ~(size_t)255;
    return p;
  };
  unsigned short* wt2 = (unsigned short*)(ws + alloc((size_t)NC * D * 2));
  unsigned short* hw = (unsigned short*)(ws + alloc((size_t)D * D * 2));
  float* s1acc = (float*)(ws + alloc((size_t)BATCH * MG * D * 4)); // 3 MB
  float* s2acc = (float*)(ws + alloc((size_t)BATCH * MG * D * 4)); // contiguous after s1acc
  float* outpre = (float*)(ws + alloc((size_t)BATCH * MG * D * 4));
  int* csr_rows = (int*)(ws + alloc((size_t)NROWS * 4));
  int* grp_sorted = (int*)(ws + alloc((size_t)NROWS * 4));

  k_prep<<<dim3(96), dim3(1024), 0, stream>>>(ii, g_w, f_w, h_w, wt2, hw, csr_rows,
                                              grp_sorted, s1acc);
  k_gemm1<<<dim3(512), dim3(512), 0, stream>>>(x, wt2, g_b, f_b, csr_rows, grp_sorted,
                                               s1acc, s2acc);
  k_gemm2<<<dim3(D / 64, (BATCH * MG) / 16), dim3(256), 0, stream>>>(s1acc, s2acc, hw, h_b,
                                                                     outpre);
  k_gather<<<dim3(4096), dim3(256), 0, stream>>>(outpre, ii, out);
}